// Round 2
// baseline (794.806 us; speedup 1.0000x reference)
//
#include <hip/hip_runtime.h>
#include <hip/hip_bf16.h>

#define N_PTS 131072
#define DIM   64
#define CELLS 256
#define EPSF  1e-8f

// ---------------------------------------------------------------------------
// Phase 0: per-cell norms ||p_c||^2, ||g_c||^2, gate=sigmoid(gate_logits),
// and the fused exp scale  cscale = -log2(e)/temp.
// ws layout (floats): [0..255]=pn  [256..511]=gn  [512..767]=gate  [768]=cscale
// ---------------------------------------------------------------------------
__global__ void prep_kernel(const float* __restrict__ prototypes,
                            const float* __restrict__ grid_pos,
                            const float* __restrict__ gate_logits,
                            const float* __restrict__ temp_raw,
                            float* __restrict__ ws) {
    const int c = threadIdx.x;  // 256 threads, 1 block
    const float* p = prototypes + c * DIM;
    const float* g = grid_pos   + c * DIM;
    float pn = 0.f, gn = 0.f;
#pragma unroll
    for (int k = 0; k < DIM; ++k) {
        pn = fmaf(p[k], p[k], pn);
        gn = fmaf(g[k], g[k], gn);
    }
    ws[c]             = pn;
    ws[CELLS + c]     = gn;
    ws[2 * CELLS + c] = 1.f / (1.f + expf(-gate_logits[c]));  // sigmoid
    if (c == 0) {
        float sg   = 1.f / (1.f + expf(-temp_raw[0]));
        float temp = sg * (1.f - 0.001f) + 0.001f;
        ws[3 * CELLS] = -1.4426950408889634f / temp;  // -log2(e)/temp
    }
}

// ---------------------------------------------------------------------------
// Main kernel: one thread per point. Phase-split so only ONE wave-uniform
// row (P_c or G_c) is live per inner loop -> rows fit the SGPR budget and
// every FMA takes the row element as a free scalar operand.
//
//   pass A (c-loop): dotp (P row), then dotg (G row), e = exp2(d*cscale),
//                    t = e*gate -> store UNSCALED t to w-row; accumulate s1,sg.
//   pass B (c-loop): v = t*alpha (read-back, L2/L3-hot), store final w,
//                    blended[d] += v * P_c[d]  (alpha pre-folded).
// ---------------------------------------------------------------------------
__global__ __launch_bounds__(256, 2)
void som_kernel(const float* __restrict__ x,
                const float* __restrict__ P,
                const float* __restrict__ G,
                const float* __restrict__ ws,
                float* __restrict__ out) {
    const int i = blockIdx.x * 256 + threadIdx.x;

    // ---- load x row into registers (16 x float4) ----
    const float* xr = x + (size_t)i * DIM;
    float xv[DIM];
#pragma unroll
    for (int k = 0; k < DIM; k += 4) {
        float4 v = *reinterpret_cast<const float4*>(xr + k);
        xv[k] = v.x; xv[k + 1] = v.y; xv[k + 2] = v.z; xv[k + 3] = v.w;
    }
    float xn = 0.f;
#pragma unroll
    for (int k = 0; k < DIM; ++k) xn = fmaf(xv[k], xv[k], xn);

    const float cscale = ws[3 * CELLS];

    float s1 = 0.f, sg = 0.f;
    float* wrow = out + (size_t)N_PTS * DIM + (size_t)i * CELLS;

    // ================= pass A: distances + unscaled weights =================
#pragma unroll 1
    for (int c0 = 0; c0 < CELLS; c0 += 4) {
        float tb[4];
#pragma unroll
        for (int cc = 0; cc < 4; ++cc) {
            const int c = c0 + cc;

            // --- dot(x, P_c): only P row live here (wave-uniform -> s_load)
            const float* pr = P + c * DIM;
            float ap0 = 0.f, ap1 = 0.f, ap2 = 0.f, ap3 = 0.f;
#pragma unroll
            for (int k = 0; k < DIM; k += 4) {
                ap0 = fmaf(xv[k + 0], pr[k + 0], ap0);
                ap1 = fmaf(xv[k + 1], pr[k + 1], ap1);
                ap2 = fmaf(xv[k + 2], pr[k + 2], ap2);
                ap3 = fmaf(xv[k + 3], pr[k + 3], ap3);
            }
            float dotp = (ap0 + ap1) + (ap2 + ap3);

            // --- dot(x, G_c): only G row live here
            const float* gr = G + c * DIM;
            float ag0 = 0.f, ag1 = 0.f, ag2 = 0.f, ag3 = 0.f;
#pragma unroll
            for (int k = 0; k < DIM; k += 4) {
                ag0 = fmaf(xv[k + 0], gr[k + 0], ag0);
                ag1 = fmaf(xv[k + 1], gr[k + 1], ag1);
                ag2 = fmaf(xv[k + 2], gr[k + 2], ag2);
                ag3 = fmaf(xv[k + 3], gr[k + 3], ag3);
            }
            float dotg = (ag0 + ag1) + (ag2 + ag3);

            float dp2 = fmaf(-2.f, dotp, xn + ws[c]);
            float dg2 = fmaf(-2.f, dotg, xn + ws[CELLS + c]);
            float d_total = sqrtf(fmaxf(dp2, 0.f)) + sqrtf(fmaxf(dg2, 0.f));
            float e = exp2f(d_total * cscale);   // = exp(-d_total/temp)
            s1 += e;
            float t = e * ws[2 * CELLS + c];     // e * gate[c]
            sg += t;
            tb[cc] = t;
        }
        *reinterpret_cast<float4*>(wrow + c0) =
            make_float4(tb[0], tb[1], tb[2], tb[3]);
    }

    // ---- normalization constants, exactly mirroring the reference ----
    // ref: w1 = e/(s1+eps); t1 = w1*gate; s2 = sum t1; w2 = t1/(s2+eps)
    //   => w2[c] = (e[c]*gate[c]) * alpha,  alpha = 1/((s1+eps)*(s2+eps))
    const float A     = s1 + EPSF;
    const float s2    = sg / A;
    const float alpha = 1.f / (A * (s2 + EPSF));

    // ================= pass B: finalize w + blend (alpha folded) ============
    float b[DIM];
#pragma unroll
    for (int d = 0; d < DIM; ++d) b[d] = 0.f;

#pragma unroll 1
    for (int c0 = 0; c0 < CELLS; c0 += 4) {
        float4 tv = *reinterpret_cast<float4*>(wrow + c0);  // L2/L3-hot
        tv.x *= alpha; tv.y *= alpha; tv.z *= alpha; tv.w *= alpha;
        *reinterpret_cast<float4*>(wrow + c0) = tv;
        const float vcc[4] = {tv.x, tv.y, tv.z, tv.w};
#pragma unroll
        for (int cc = 0; cc < 4; ++cc) {
            const float* pr = P + (c0 + cc) * DIM;  // only P row live here
            const float v = vcc[cc];
#pragma unroll
            for (int d = 0; d < DIM; ++d) b[d] = fmaf(v, pr[d], b[d]);
        }
    }

    // ---- blended output (already scaled: alpha folded into v) ----
    float* brow = out + (size_t)i * DIM;
#pragma unroll
    for (int d = 0; d < DIM; d += 4) {
        *reinterpret_cast<float4*>(brow + d) =
            make_float4(b[d], b[d + 1], b[d + 2], b[d + 3]);
    }
}

extern "C" void kernel_launch(void* const* d_in, const int* in_sizes, int n_in,
                              void* d_out, int out_size, void* d_ws, size_t ws_size,
                              hipStream_t stream) {
    const float* x           = (const float*)d_in[0];
    const float* prototypes  = (const float*)d_in[1];
    const float* grid_pos    = (const float*)d_in[2];
    const float* gate_logits = (const float*)d_in[3];
    const float* temp_raw    = (const float*)d_in[4];
    float*       out         = (float*)d_out;
    float*       ws          = (float*)d_ws;

    prep_kernel<<<1, CELLS, 0, stream>>>(prototypes, grid_pos, gate_logits,
                                         temp_raw, ws);
    som_kernel<<<N_PTS / 256, 256, 0, stream>>>(x, prototypes, grid_pos, ws, out);
}